// Round 1
// baseline (332.350 us; speedup 1.0000x reference)
//
#include <hip/hip_runtime.h>
#include <cstdint>
#include <cstddef>

constexpr int D = 64;
constexpr int TWO_D = 128;

// ---------------------------------------------------------------------------
// Kernel 1: projection tables.
//   rows [0, NV):        P[v,:]  = v_to_e[v,:] . att1_w[:, 0:D]^T          (per d)
//   rows [NV, NV+B):     S[b,:]  = u_to_e[nodes[b],:] . att1_w[:, D:2D]^T + att1_b
// One wave per row; lane = output feature d. Input row is wave-uniform
// (scalar loads); each lane holds its W1 row slice.
// ---------------------------------------------------------------------------
__global__ __launch_bounds__(256) void proj_kernel(
    const float* __restrict__ v_to_e, const float* __restrict__ u_to_e,
    const int* __restrict__ nodes,
    const float* __restrict__ att1_w, const float* __restrict__ att1_b,
    float* __restrict__ P, float* __restrict__ S, int NV, int Bn)
{
    const int wid  = (int)((blockIdx.x * blockDim.x + threadIdx.x) >> 6);
    const int lane = threadIdx.x & 63;
    if (wid >= NV + Bn) return;

    const bool isP = (wid < NV);
    const float4* x4;
    const float4* w4;
    float a0;
    if (isP) {
        x4 = (const float4*)(v_to_e + (size_t)wid * D);
        w4 = (const float4*)(att1_w + lane * TWO_D);
        a0 = 0.f;
    } else {
        const int b = wid - NV;
        x4 = (const float4*)(u_to_e + (size_t)nodes[b] * D);
        w4 = (const float4*)(att1_w + lane * TWO_D + D);
        a0 = att1_b[lane];
    }
    float a1 = 0.f, a2 = 0.f, a3 = 0.f;
#pragma unroll
    for (int i = 0; i < D / 4; ++i) {
        float4 x = x4[i];   // wave-uniform -> s_load
        float4 w = w4[i];   // per-lane
        a0 += x.x * w.x; a1 += x.y * w.y; a2 += x.z * w.z; a3 += x.w * w.w;
    }
    const float acc = (a0 + a1) + (a2 + a3);
    if (isP) P[(size_t)wid * D + lane] = acc;
    else     S[(size_t)(wid - NV) * D + lane] = acc;
}

// ---------------------------------------------------------------------------
// Kernel 2: one wave per node b. Lane k owns neighbor k (k < K=50; 50..63 idle
// compute, masked in softmax). h1 row lives in 64 VGPRs per lane; att2/att3
// weights are wave-uniform (scalar loads). Softmax via shuffle reduce; final
// weighted sum re-gathers v_to_e rows coalesced with lane = d.
// ---------------------------------------------------------------------------
template <bool HAS_WS>
__global__ __launch_bounds__(256) void agg_kernel(
    const int* __restrict__ nodes, const int* __restrict__ history,
    const int* __restrict__ degrees,
    const float* __restrict__ u_to_e, const float* __restrict__ v_to_e,
    const float* __restrict__ att1_w, const float* __restrict__ att1_b,
    const float* __restrict__ att2_w, const float* __restrict__ att2_b,
    const float* __restrict__ att3_w, const float* __restrict__ att3_b,
    const float* __restrict__ P, const float* __restrict__ S,
    float* __restrict__ out, int Bn, int K)
{
    const int b    = (int)((blockIdx.x * blockDim.x + threadIdx.x) >> 6);
    const int lane = threadIdx.x & 63;
    if (b >= Bn) return;

    const int  deg    = degrees[b];            // wave-uniform
    const int  k      = lane;
    const bool active = (k < deg);
    const int  v      = history[(size_t)b * K + ((k < K) ? k : 0)];

    // ---- phase A: h1 = relu(P[v] + S[b]) ----
    float h1[D];
    if (HAS_WS) {
        const float4* p4 = (const float4*)(P + (size_t)v * D);
        const float4* s4 = (const float4*)(S + (size_t)b * D);  // uniform
#pragma unroll
        for (int i = 0; i < D / 4; ++i) {
            float4 p = p4[i];
            float4 s = s4[i];
            h1[4 * i + 0] = fmaxf(p.x + s.x, 0.f);
            h1[4 * i + 1] = fmaxf(p.y + s.y, 0.f);
            h1[4 * i + 2] = fmaxf(p.z + s.z, 0.f);
            h1[4 * i + 3] = fmaxf(p.w + s.w, 0.f);
        }
    } else {
        // fallback: compute h1 on the fly (no workspace)
        float vr[D];
        const float4* v4 = (const float4*)(v_to_e + (size_t)v * D);
#pragma unroll
        for (int i = 0; i < D / 4; ++i) {
            float4 t = v4[i];
            vr[4 * i + 0] = t.x; vr[4 * i + 1] = t.y;
            vr[4 * i + 2] = t.z; vr[4 * i + 3] = t.w;
        }
        const float* urow = u_to_e + (size_t)nodes[b] * D;  // uniform
#pragma unroll
        for (int d = 0; d < D; ++d) {
            const float* w1 = att1_w + d * TWO_D;
            float a0 = att1_b[d], a1 = 0.f, a2 = 0.f, a3 = 0.f;
#pragma unroll
            for (int f = 0; f < D; f += 4) {
                a0 += vr[f + 0] * w1[f + 0];
                a1 += vr[f + 1] * w1[f + 1];
                a2 += vr[f + 2] * w1[f + 2];
                a3 += vr[f + 3] * w1[f + 3];
                a0 += urow[f + 0] * w1[D + f + 0];
                a1 += urow[f + 1] * w1[D + f + 1];
                a2 += urow[f + 2] * w1[D + f + 2];
                a3 += urow[f + 3] * w1[D + f + 3];
            }
            h1[d] = fmaxf((a0 + a1) + (a2 + a3), 0.f);
        }
    }

    // ---- phase B: logit = b3 + w3 . relu(W2 . h1 + b2) ----
    float logit = att3_b[0];
#pragma unroll 2
    for (int e = 0; e < D; ++e) {
        const float* w2r = att2_w + e * D;   // wave-uniform row -> s_load
        float a0 = 0.f, a1 = 0.f, a2 = 0.f, a3 = 0.f;
#pragma unroll
        for (int dd = 0; dd < D; dd += 4) {
            a0 += h1[dd + 0] * w2r[dd + 0];
            a1 += h1[dd + 1] * w2r[dd + 1];
            a2 += h1[dd + 2] * w2r[dd + 2];
            a3 += h1[dd + 3] * w2r[dd + 3];
        }
        float h2 = (a0 + a1) + (a2 + a3) + att2_b[e];
        h2 = fmaxf(h2, 0.f);
        logit += h2 * att3_w[e];
    }

    // ---- phase C: masked softmax across lanes (ragged neighbor set) ----
    float ml = active ? logit : -1e30f;
#pragma unroll
    for (int off = 32; off > 0; off >>= 1)
        ml = fmaxf(ml, __shfl_xor(ml, off));
    const float ex = active ? __expf(logit - ml) : 0.f;
    float sm = ex;
#pragma unroll
    for (int off = 32; off > 0; off >>= 1)
        sm += __shfl_xor(sm, off);
    const float att = ex / sm;

    // ---- phase D: out[b, lane] = sum_k att_k * v_to_e[v_k, lane] ----
    float acc = 0.f;
    for (int kk = 0; kk < deg; ++kk) {
        const float a  = __shfl(att, kk);
        const int   vk = __shfl(v, kk);
        acc += a * v_to_e[(size_t)vk * D + lane];
    }
    out[(size_t)b * D + lane] = acc;
}

// ---------------------------------------------------------------------------
extern "C" void kernel_launch(void* const* d_in, const int* in_sizes, int n_in,
                              void* d_out, int out_size, void* d_ws, size_t ws_size,
                              hipStream_t stream)
{
    const int*   nodes   = (const int*)d_in[0];
    const int*   history = (const int*)d_in[1];
    const int*   degrees = (const int*)d_in[2];
    const float* u_to_e  = (const float*)d_in[3];
    const float* v_to_e  = (const float*)d_in[4];
    const float* att1_w  = (const float*)d_in[5];
    const float* att1_b  = (const float*)d_in[6];
    const float* att2_w  = (const float*)d_in[7];
    const float* att2_b  = (const float*)d_in[8];
    const float* att3_w  = (const float*)d_in[9];
    const float* att3_b  = (const float*)d_in[10];
    float*       out     = (float*)d_out;

    const int Bn = in_sizes[0];
    const int K  = in_sizes[1] / Bn;
    const int NV = in_sizes[4] / D;

    const size_t need = ((size_t)NV + (size_t)Bn) * D * sizeof(float);

    const int agg_blocks = (Bn * 64 + 255) / 256;

    if (ws_size >= need) {
        float* P = (float*)d_ws;
        float* S = P + (size_t)NV * D;
        const int rows        = NV + Bn;
        const int proj_blocks = (rows * 64 + 255) / 256;
        proj_kernel<<<proj_blocks, 256, 0, stream>>>(
            v_to_e, u_to_e, nodes, att1_w, att1_b, P, S, NV, Bn);
        agg_kernel<true><<<agg_blocks, 256, 0, stream>>>(
            nodes, history, degrees, u_to_e, v_to_e,
            att1_w, att1_b, att2_w, att2_b, att3_w, att3_b,
            P, S, out, Bn, K);
    } else {
        agg_kernel<false><<<agg_blocks, 256, 0, stream>>>(
            nodes, history, degrees, u_to_e, v_to_e,
            att1_w, att1_b, att2_w, att2_b, att3_w, att3_b,
            nullptr, nullptr, out, Bn, K);
    }
}